// Round 20
// baseline (216.228 us; speedup 1.0000x reference)
//
#include <hip/hip_runtime.h>
#include <hip/hip_bf16.h>

#define B_   8
#define N_   8192
#define S_   2048
#define D1_  128
#define D2_  256
#define CIN_ 384
#define C1_  256
#define C2_  128
#define ROWS_ (B_ * N_)   // 65536

typedef __attribute__((ext_vector_type(8))) short short8v;
typedef __attribute__((ext_vector_type(4))) float f32x4;
typedef __attribute__((ext_vector_type(16))) float f32x16;

__device__ inline unsigned short f2bf(float x) {
    __hip_bfloat16 h = __float2bfloat16(x);
    unsigned short u;
    __builtin_memcpy(&u, &h, 2);
    return u;
}
__device__ inline float bf2f(unsigned short u) {
    unsigned int x = ((unsigned int)u) << 16;
    float f;
    __builtin_memcpy(&f, &x, 4);
    return f;
}
__device__ inline unsigned int f2u(float x) { unsigned int u; __builtin_memcpy(&u, &x, 4); return u; }
__device__ inline float u2f(unsigned int u) { float x; __builtin_memcpy(&x, &u, 4); return x; }

// ---------------------------------------------------------------------------
// Pack xyz2 -> {x,y,z,r2} float4 (passed rounds 9-18; r2 bit-identical)
// ---------------------------------------------------------------------------
__global__ __launch_bounds__(256) void pack_kernel(
    const float* __restrict__ xyz2, float4* __restrict__ pk)
{
#pragma clang fp contract(off)
    int i = blockIdx.x * 256 + threadIdx.x;
    float a = xyz2[i * 3 + 0], c = xyz2[i * 3 + 1], d = xyz2[i * 3 + 2];
    float4 v; v.x = a; v.y = c; v.z = d; v.w = (a * a + c * c) + d * d;
    pk[i] = v;
}

// ---------------------------------------------------------------------------
// 3-NN single-pass (byte-identical to passing rounds 13/14/18)
// ---------------------------------------------------------------------------
__global__ __launch_bounds__(1024) void nn3_kernel(
    const float* __restrict__ xyz1, const float4* __restrict__ pk,
    int* __restrict__ nidx, float* __restrict__ nw)
{
#pragma clang fp contract(off)
    __shared__ unsigned int pv[8][128][3];
    __shared__ int          pi[8][128][3];
    const int tid = threadIdx.x;
    const int b = blockIdx.y;
    const int q = tid & 127;
    const int chunk = tid >> 7;
    const int s0 = chunk * 256;
    const unsigned s0u = __builtin_amdgcn_readfirstlane((unsigned)s0);
    const char* cp = (const char*)(pk + (size_t)b * S_) + (size_t)s0u * 16u;

    const int n = blockIdx.x * 128 + q;
    const float* p = xyz1 + ((size_t)b * N_ + n) * 3;
    const float px = p[0], py = p[1], pz = p[2];
    const float r1 = (px * px + py * py) + pz * pz;

    float e1 = 3.4e38f, e2 = 3.4e38f, e3 = 3.4e38f;
    int i1 = 0x7FFFFFFF, i2 = 0x7FFFFFFF, i3 = 0x7FFFFFFF;
    for (int g = 0; g < 16; ++g) {
        f32x16 c0, c1, c2, c3;
        asm volatile("s_load_dwordx16 %0, %4, 0\n\t"
                     "s_load_dwordx16 %1, %4, 64\n\t"
                     "s_load_dwordx16 %2, %4, 128\n\t"
                     "s_load_dwordx16 %3, %4, 192\n\t"
                     "s_waitcnt lgkmcnt(0)"
                     : "=&s"(c0), "=&s"(c1), "=&s"(c2), "=&s"(c3)
                     : "s"(cp + (size_t)g * 256));
#pragma unroll
        for (int j = 0; j < 16; ++j) {
            float sx = (j < 4) ? c0[4*j+0] : (j < 8) ? c1[4*(j-4)+0] : (j < 12) ? c2[4*(j-8)+0] : c3[4*(j-12)+0];
            float sy = (j < 4) ? c0[4*j+1] : (j < 8) ? c1[4*(j-4)+1] : (j < 12) ? c2[4*(j-8)+1] : c3[4*(j-12)+1];
            float sz = (j < 4) ? c0[4*j+2] : (j < 8) ? c1[4*(j-4)+2] : (j < 12) ? c2[4*(j-8)+2] : c3[4*(j-12)+2];
            float sr = (j < 4) ? c0[4*j+3] : (j < 8) ? c1[4*(j-4)+3] : (j < 12) ? c2[4*(j-8)+3] : c3[4*(j-12)+3];
            float dot = (px * sx + py * sy) + pz * sz;
            float d = (r1 - 2.0f * dot) + sr;
            const int s = s0 + g * 16 + j;
            bool lt1 = d < e1, lt2 = d < e2, lt3 = d < e3;
            float n1 = fminf(e1, d);
            float n2 = __builtin_amdgcn_fmed3f(d, e1, e2);
            float n3 = __builtin_amdgcn_fmed3f(d, e2, e3);
            int ni1 = lt1 ? s : i1;
            int ni2 = lt1 ? i1 : (lt2 ? s : i2);
            int ni3 = lt2 ? i2 : (lt3 ? s : i3);
            e1 = n1; e2 = n2; e3 = n3;
            i1 = ni1; i2 = ni2; i3 = ni3;
        }
    }
    pv[chunk][q][0] = f2u(e1); pv[chunk][q][1] = f2u(e2); pv[chunk][q][2] = f2u(e3);
    pi[chunk][q][0] = i1; pi[chunk][q][1] = i2; pi[chunk][q][2] = i3;
    __syncthreads();

    if (tid < 128) {
        float m1 = u2f(pv[0][tid][0]), m2 = u2f(pv[0][tid][1]), m3 = u2f(pv[0][tid][2]);
        int j1 = pi[0][tid][0], j2 = pi[0][tid][1], j3 = pi[0][tid][2];
#pragma unroll
        for (int c = 1; c < 8; ++c) {
#pragma unroll
            for (int e = 0; e < 3; ++e) {
                float x = u2f(pv[c][tid][e]);
                int   xi = pi[c][tid][e];
                bool lt1 = x < m1, lt2 = x < m2, lt3 = x < m3;
                float n1 = fminf(m1, x);
                float n2 = __builtin_amdgcn_fmed3f(x, m1, m2);
                float n3 = __builtin_amdgcn_fmed3f(x, m2, m3);
                int nj1 = lt1 ? xi : j1;
                int nj2 = lt1 ? j1 : (lt2 ? xi : j2);
                int nj3 = lt2 ? j2 : (lt3 ? xi : j3);
                m1 = n1; m2 = n2; m3 = n3;
                j1 = nj1; j2 = nj2; j3 = nj3;
            }
        }
        float ra = 1.0f / (m1 + 1e-8f);
        float rb = 1.0f / (m2 + 1e-8f);
        float rc = 1.0f / (m3 + 1e-8f);
        float sum = (ra + rb) + rc;
        size_t o = ((size_t)b * N_ + blockIdx.x * 128 + tid) * 3;
        nidx[o + 0] = j1; nidx[o + 1] = j2; nidx[o + 2] = j3;
        nw[o + 0] = ra / sum; nw[o + 1] = rb / sum; nw[o + 2] = rc / sum;
    }
}

// weights -> bf16
__global__ void cvtw_kernel(const float* __restrict__ w1, const float* __restrict__ w2,
                            unsigned short* __restrict__ w1b, unsigned short* __restrict__ w2b)
{
    int i = blockIdx.x * 256 + threadIdx.x;
    if (i < C1_ * CIN_) w1b[i] = f2bf(w1[i]);
    else {
        int j = i - C1_ * CIN_;
        if (j < C2_ * C1_) w2b[j] = f2bf(w2[j]);
    }
}

// ---------------------------------------------------------------------------
// GEMM1 PIPELINED: BM=128 x BN=256 x BK=64, 8 waves, grid 512.
// Software pipeline: raw A-gather loads for step k+1 issued BEFORE step k's
// MFMA block; compiler's vmcnt drain lands at the next barrier (post-MFMA),
// hiding gather latency under 32 MFMAs. acc[4][4]=64 VGPR + 48 raw VGPR
// fits under the launch_bounds(512,2) 256-VGPR cap (r13's failure mode was
// the 128-cap demotion). A-build arithmetic bit-identical to r14/r18.
// ---------------------------------------------------------------------------
__global__ __launch_bounds__(512, 2) void gemm1_kernel(
    const unsigned short* __restrict__ W,    // w1b [256][384]
    const float* __restrict__ bias,
    const float* __restrict__ p1,
    const float* __restrict__ p2,
    const int* __restrict__ nidx,
    const float* __restrict__ nw,
    unsigned short* __restrict__ out,        // y1b [65536][256]
    float* __restrict__ sums, float* __restrict__ ssqs)
{
    __shared__ unsigned short As[8][128][8];   // 16 KiB
    __shared__ unsigned short Bs[8][256][8];   // 32 KiB
    __shared__ float csum[256], csq[256];
    __shared__ int   lidx[128][3];
    __shared__ float lw[128][3];
    const int tid = threadIdx.x;               // 0..511
    const int wave = tid >> 6, lane = tid & 63;
    const int chunkw = (blockIdx.x & 7) * (gridDim.x >> 3) + (blockIdx.x >> 3);
    const int r0 = chunkw * 128;
    const int wr = wave >> 2, wc = wave & 3;   // wr 0..1, wc 0..3
    const int kh = lane >> 4, l16 = lane & 15;
    const int irow = tid & 127;                // row this thread stages
    const int kgb = (tid >> 7) * 2;            // octet base: 0,2,4,6

    if (tid < 128) {
        const int row = r0 + tid;
        lidx[tid][0] = nidx[row * 3 + 0];
        lidx[tid][1] = nidx[row * 3 + 1];
        lidx[tid][2] = nidx[row * 3 + 2];
        lw[tid][0] = nw[row * 3 + 0];
        lw[tid][1] = nw[row * 3 + 1];
        lw[tid][2] = nw[row * 3 + 2];
    }
    if (tid < 256) { csum[tid] = 0.f; csq[tid] = 0.f; }
    __syncthreads();
    const int gj0 = lidx[irow][0], gj1 = lidx[irow][1], gj2 = lidx[irow][2];
    const float gw0 = lw[irow][0], gw1 = lw[irow][1], gw2 = lw[irow][2];
    const float* p2b = p2 + (size_t)(r0 >> 13) * S_ * D2_;   // block-uniform batch

    f32x4 acc[4][4];
#pragma unroll
    for (int m = 0; m < 4; ++m)
#pragma unroll
        for (int n = 0; n < 4; ++n)
            acc[m][n] = (f32x4){0.f, 0.f, 0.f, 0.f};

    float4 rw[2][6];   // in-flight raw gather data [octet][slot]

    // issue raw loads for step kn (no wait here)
    auto loadraw = [&](int kn) {
#pragma unroll
        for (int t = 0; t < 2; ++t) {
            const int kg = kgb + t;
            const int cc0 = kn + kg * 8;
            if (kn < D1_) {
                const float* qq = p1 + (size_t)(r0 + irow) * D1_ + cc0;
                rw[t][0] = *(const float4*)qq;
                rw[t][1] = *(const float4*)(qq + 4);
            } else {
                const int cc = cc0 - D1_;
                const float* q0 = p2b + (size_t)gj0 * D2_ + cc;
                const float* q1 = p2b + (size_t)gj1 * D2_ + cc;
                const float* q2 = p2b + (size_t)gj2 * D2_ + cc;
                rw[t][0] = *(const float4*)q0; rw[t][1] = *(const float4*)(q0 + 4);
                rw[t][2] = *(const float4*)q1; rw[t][3] = *(const float4*)(q1 + 4);
                rw[t][4] = *(const float4*)q2; rw[t][5] = *(const float4*)(q2 + 4);
            }
        }
    };
    // convert raw -> bf16, write A-tile to LDS (arithmetic identical to r14)
    auto convA = [&](int kn) {
#pragma unroll
        for (int t = 0; t < 2; ++t) {
            const int kg = kgb + t;
            short8v r;
            if (kn < D1_) {
                float tt[8] = {rw[t][0].x, rw[t][0].y, rw[t][0].z, rw[t][0].w,
                               rw[t][1].x, rw[t][1].y, rw[t][1].z, rw[t][1].w};
#pragma unroll
                for (int j = 0; j < 8; ++j) r[j] = (short)f2bf(tt[j]);
            } else {
                float a0[8] = {rw[t][0].x, rw[t][0].y, rw[t][0].z, rw[t][0].w,
                               rw[t][1].x, rw[t][1].y, rw[t][1].z, rw[t][1].w};
                float a1[8] = {rw[t][2].x, rw[t][2].y, rw[t][2].z, rw[t][2].w,
                               rw[t][3].x, rw[t][3].y, rw[t][3].z, rw[t][3].w};
                float a2[8] = {rw[t][4].x, rw[t][4].y, rw[t][4].z, rw[t][4].w,
                               rw[t][5].x, rw[t][5].y, rw[t][5].z, rw[t][5].w};
#pragma unroll
                for (int j = 0; j < 8; ++j)
                    r[j] = (short)f2bf(a0[j] * gw0 + a1[j] * gw1 + a2[j] * gw2);
            }
            *(short8v*)&As[kg][irow][0] = r;
        }
    };

    loadraw(0);   // prologue

    for (int k0 = 0; k0 < CIN_; k0 += 64) {
        __syncthreads();   // previous step's LDS reads complete
        // stage B: 2048 slots (8 octets x 256 cols), 4 gload_lds per thread
#pragma unroll
        for (int t = 0; t < 4; ++t) {
            const int sb = t * 512 + wave * 64;          // wave-uniform
            const int s = sb + lane;
            const int bkg = s >> 8, bi = s & 255;
            const unsigned short* gB = W + (size_t)bi * CIN_ + k0 + bkg * 8;
            __builtin_amdgcn_global_load_lds(
                (const __attribute__((address_space(1))) void*)gB,
                (__attribute__((address_space(3))) void*)(&Bs[0][0][0] + (size_t)sb * 8),
                16, 0, 0);
        }
        convA(k0);         // raw data landed during previous MFMA phase
        __syncthreads();

        if (k0 + 64 < CIN_) loadraw(k0 + 64);   // issue next step's gathers

        // MFMA: 2 K=32 chunks, 4x4 frags -> 32 MFMA/wave/step (hides loads)
#pragma unroll
        for (int kk = 0; kk < 2; ++kk) {
            short8v af[4], bf[4];
#pragma unroll
            for (int m = 0; m < 4; ++m)
                af[m] = *(const short8v*)&As[kk * 4 + kh][wr * 64 + m * 16 + l16][0];
#pragma unroll
            for (int n = 0; n < 4; ++n)
                bf[n] = *(const short8v*)&Bs[kk * 4 + kh][wc * 64 + n * 16 + l16][0];
#pragma unroll
            for (int m = 0; m < 4; ++m)
#pragma unroll
                for (int n = 0; n < 4; ++n)
                    acc[m][n] = __builtin_amdgcn_mfma_f32_16x16x32_bf16(
                        af[m], bf[n], acc[m][n], 0, 0, 0);
        }
    }

    // epilogue: +bias, store, per-channel stats (values identical to r14)
#pragma unroll
    for (int n = 0; n < 4; ++n) {
        const int col = wc * 64 + n * 16 + l16;   // 0..255
        const float bv = bias[col];
        float s = 0.f, qs = 0.f;
#pragma unroll
        for (int m = 0; m < 4; ++m) {
            const int rl = wr * 64 + m * 16 + kh * 4;   // 0..127
#pragma unroll
            for (int j = 0; j < 4; ++j) {
                const float v = acc[m][n][j] + bv;
                s += v; qs += v * v;
                out[(size_t)(r0 + rl + j) * C1_ + col] = f2bf(v);
            }
        }
        atomicAdd(&csum[col], s);
        atomicAdd(&csq[col], qs);
    }
    __syncthreads();
    if (tid < 256) {
        atomicAdd(&sums[tid], csum[tid]);
        atomicAdd(&ssqs[tid], csq[tid]);
    }
}

// ---------------------------------------------------------------------------
// GEMM2 (byte-identical to passing rounds 10-18)
// ---------------------------------------------------------------------------
__global__ __launch_bounds__(256) void gemm2_kernel(
    const unsigned short* __restrict__ Abf,
    const unsigned short* __restrict__ W,
    const float* __restrict__ bias,
    const float* __restrict__ scale, const float* __restrict__ shift,
    float* __restrict__ outf,
    float* __restrict__ sums, float* __restrict__ ssqs)
{
    __shared__ unsigned short As[4][128][8];
    __shared__ unsigned short Bs[4][128][8];
    __shared__ float csum[128], csq[128];
    const int tid = threadIdx.x;
    const int wave = tid >> 6, lane = tid & 63;
    const int chunkw = (blockIdx.x & 7) * (gridDim.x >> 3) + (blockIdx.x >> 3);
    const int r0 = chunkw * 128;
    const int n0 = 0;
    const int wr = wave >> 1, wc = wave & 1;
    const int kh = lane >> 4, l16 = lane & 15;

    if (tid < 128) { csum[tid] = 0.f; csq[tid] = 0.f; }

    f32x4 acc[4][4];
#pragma unroll
    for (int m = 0; m < 4; ++m)
#pragma unroll
        for (int n = 0; n < 4; ++n)
            acc[m][n] = (f32x4){0.f, 0.f, 0.f, 0.f};

    const int slotbase = wave * 64;
    int rowA[2];
#pragma unroll
    for (int pp = 0; pp < 2; ++pp)
        rowA[pp] = r0 + ((pp * 256 + slotbase + lane) & 127);

    for (int k0 = 0; k0 < C1_; k0 += 32) {
        __syncthreads();
#pragma unroll
        for (int pp = 0; pp < 2; ++pp) {
            const int sb = pp * 256 + slotbase;
            const int s = sb + lane;
            const int kg = s >> 7, i = s & 127;
            const unsigned short* gB = W + (size_t)(n0 + i) * C1_ + k0 + kg * 8;
            __builtin_amdgcn_global_load_lds(
                (const __attribute__((address_space(1))) void*)gB,
                (__attribute__((address_space(3))) void*)(&Bs[0][0][0] + (size_t)sb * 8),
                16, 0, 0);
            const int c0 = k0 + kg * 8;
            short8v v = *(const short8v*)(Abf + (size_t)rowA[pp] * C1_ + c0);
            float4 sca = *(const float4*)(scale + c0);
            float4 scb = *(const float4*)(scale + c0 + 4);
            float4 sha = *(const float4*)(shift + c0);
            float4 shb = *(const float4*)(shift + c0 + 4);
            float sc[8] = {sca.x, sca.y, sca.z, sca.w, scb.x, scb.y, scb.z, scb.w};
            float sh[8] = {sha.x, sha.y, sha.z, sha.w, shb.x, shb.y, shb.z, shb.w};
            short8v r;
#pragma unroll
            for (int j = 0; j < 8; ++j) {
                float f = bf2f((unsigned short)v[j]);
                f = fmaxf(fmaf(f, sc[j], sh[j]), 0.0f);
                r[j] = (short)f2bf(f);
            }
            *(short8v*)&As[kg][s & 127][0] = r;
        }
        __syncthreads();

        short8v af[4], bf[4];
#pragma unroll
        for (int m = 0; m < 4; ++m)
            af[m] = *(const short8v*)&As[kh][wr * 64 + m * 16 + l16][0];
#pragma unroll
        for (int n = 0; n < 4; ++n)
            bf[n] = *(const short8v*)&Bs[kh][wc * 64 + n * 16 + l16][0];
#pragma unroll
        for (int m = 0; m < 4; ++m)
#pragma unroll
            for (int n = 0; n < 4; ++n)
                acc[m][n] = __builtin_amdgcn_mfma_f32_16x16x32_bf16(
                    af[m], bf[n], acc[m][n], 0, 0, 0);
    }

#pragma unroll
    for (int n = 0; n < 4; ++n) {
        const int cl = wc * 64 + n * 16 + l16;
        const int col = n0 + cl;
        const float bv = bias[col];
        float s = 0.f, qs = 0.f;
#pragma unroll
        for (int m = 0; m < 4; ++m) {
            const int rowb = r0 + wr * 64 + m * 16 + kh * 4;
#pragma unroll
            for (int j = 0; j < 4; ++j) {
                const float v = acc[m][n][j] + bv;
                s += v; qs += v * v;
                outf[(size_t)(rowb + j) * C2_ + col] = v;
            }
        }
        atomicAdd(&csum[cl], s);
        atomicAdd(&csq[cl], qs);
    }
    __syncthreads();
    if (tid < 128) {
        atomicAdd(&sums[n0 + tid], csum[tid]);
        atomicAdd(&ssqs[n0 + tid], csq[tid]);
    }
}

__global__ void finalize_kernel(const float* __restrict__ sums,
                                const float* __restrict__ ssqs,
                                const float* __restrict__ g,
                                const float* __restrict__ be,
                                float* __restrict__ scale,
                                float* __restrict__ shift, int C, float invCnt)
{
    int c = threadIdx.x;
    if (c < C) {
        float mu = sums[c] * invCnt;
        float var = ssqs[c] * invCnt - mu * mu;
        float sc = g[c] / sqrtf(var + 1e-5f);
        scale[c] = sc;
        shift[c] = be[c] - mu * sc;
    }
}

__global__ __launch_bounds__(256) void bnrelu_store_kernel(
    const float* __restrict__ y, const float* __restrict__ scale,
    const float* __restrict__ shift, float* __restrict__ out)
{
    int i = blockIdx.x * 256 + threadIdx.x;
    float4 v = ((const float4*)y)[i];
    int o = (i * 4) & (C2_ - 1);
    float4 sc = *(const float4*)(scale + o);
    float4 sh = *(const float4*)(shift + o);
    float4 r;
    r.x = fmaxf(fmaf(v.x, sc.x, sh.x), 0.0f);
    r.y = fmaxf(fmaf(v.y, sc.y, sh.y), 0.0f);
    r.z = fmaxf(fmaf(v.z, sc.z, sh.z), 0.0f);
    r.w = fmaxf(fmaf(v.w, sc.w, sh.w), 0.0f);
    ((float4*)out)[i] = r;
}

extern "C" void kernel_launch(void* const* d_in, const int* in_sizes, int n_in,
                              void* d_out, int out_size, void* d_ws, size_t ws_size,
                              hipStream_t stream)
{
    const float* xyz1    = (const float*)d_in[0];
    const float* xyz2    = (const float*)d_in[1];
    const float* points1 = (const float*)d_in[2];
    const float* points2 = (const float*)d_in[3];
    const float* w1  = (const float*)d_in[4];
    const float* b1  = (const float*)d_in[5];
    const float* g1  = (const float*)d_in[6];
    const float* be1 = (const float*)d_in[7];
    const float* w2  = (const float*)d_in[8];
    const float* b2  = (const float*)d_in[9];
    const float* g2  = (const float*)d_in[10];
    const float* be2 = (const float*)d_in[11];
    float* out = (float*)d_out;

    char* w = (char*)d_ws;
    float*          y2  = (float*)w;                             // 33,554,432
    unsigned short* y1b = (unsigned short*)(w + 50331648);       // 33,554,432
    char* tail = w + 83886080;
    int*   nidx = (int*)tail;                                    // 786,432
    float* nw   = (float*)(tail + 786432);                       // 786,432
    unsigned short* w1b = (unsigned short*)(tail + 1572864);     // 196,608
    unsigned short* w2b = (unsigned short*)(tail + 1769472);     // 65,536
    float* sum1   = (float*)(tail + 1835008);
    float* ssq1   = sum1 + 256;
    float* sum2   = ssq1 + 256;
    float* ssq2   = sum2 + 128;
    float* scale1 = ssq2 + 128;
    float* shift1 = scale1 + 256;
    float* scale2 = shift1 + 256;
    float* shift2 = scale2 + 128;
    float4* pk    = (float4*)(tail + 1843200);                   // 262,144

    hipMemsetAsync(sum1, 0, (256 + 256 + 128 + 128) * sizeof(float), stream);

    cvtw_kernel<<<dim3((C1_ * CIN_ + C2_ * C1_ + 255) / 256), 256, 0, stream>>>(w1, w2, w1b, w2b);
    pack_kernel<<<dim3(B_ * S_ / 256), 256, 0, stream>>>(xyz2, pk);

    nn3_kernel<<<dim3(N_ / 128, B_), 1024, 0, stream>>>(xyz1, pk, nidx, nw);

    gemm1_kernel<<<dim3(ROWS_ / 128), 512, 0, stream>>>(
        w1b, b1, points1, points2, nidx, nw, y1b, sum1, ssq1);
    finalize_kernel<<<1, 256, 0, stream>>>(sum1, ssq1, g1, be1, scale1, shift1, C1_, 1.0f / ROWS_);

    gemm2_kernel<<<dim3(ROWS_ / 128), 256, 0, stream>>>(
        y1b, w2b, b2, scale1, shift1, y2, sum2, ssq2);
    finalize_kernel<<<1, 256, 0, stream>>>(sum2, ssq2, g2, be2, scale2, shift2, C2_, 1.0f / ROWS_);

    bnrelu_store_kernel<<<dim3(ROWS_ * C2_ / 4 / 256), 256, 0, stream>>>(y2, scale2, shift2, out);
}

// Round 21
// 189.940 us; speedup vs baseline: 1.1384x; 1.1384x over previous
//
#include <hip/hip_runtime.h>
#include <hip/hip_bf16.h>

#define B_   8
#define N_   8192
#define S_   2048
#define D1_  128
#define D2_  256
#define CIN_ 384
#define C1_  256
#define C2_  128
#define ROWS_ (B_ * N_)   // 65536

typedef __attribute__((ext_vector_type(8))) short short8v;
typedef __attribute__((ext_vector_type(4))) float f32x4;
typedef __attribute__((ext_vector_type(16))) float f32x16;

__device__ inline unsigned short f2bf(float x) {
    __hip_bfloat16 h = __float2bfloat16(x);
    unsigned short u;
    __builtin_memcpy(&u, &h, 2);
    return u;
}
__device__ inline float bf2f(unsigned short u) {
    unsigned int x = ((unsigned int)u) << 16;
    float f;
    __builtin_memcpy(&f, &x, 4);
    return f;
}
__device__ inline unsigned int f2u(float x) { unsigned int u; __builtin_memcpy(&u, &x, 4); return u; }
__device__ inline float u2f(unsigned int u) { float x; __builtin_memcpy(&x, &u, 4); return x; }

// ---------------------------------------------------------------------------
// Pack xyz2 -> {x,y,z,r2} float4 (passed rounds 9-20; r2 bit-identical)
// ---------------------------------------------------------------------------
__global__ __launch_bounds__(256) void pack_kernel(
    const float* __restrict__ xyz2, float4* __restrict__ pk)
{
#pragma clang fp contract(off)
    int i = blockIdx.x * 256 + threadIdx.x;
    float a = xyz2[i * 3 + 0], c = xyz2[i * 3 + 1], d = xyz2[i * 3 + 2];
    float4 v; v.x = a; v.y = c; v.z = d; v.w = (a * a + c * c) + d * d;
    pk[i] = v;
}

// ---------------------------------------------------------------------------
// 3-NN single-pass (byte-identical to passing rounds 13/14/18)
// ---------------------------------------------------------------------------
__global__ __launch_bounds__(1024) void nn3_kernel(
    const float* __restrict__ xyz1, const float4* __restrict__ pk,
    int* __restrict__ nidx, float* __restrict__ nw)
{
#pragma clang fp contract(off)
    __shared__ unsigned int pv[8][128][3];
    __shared__ int          pi[8][128][3];
    const int tid = threadIdx.x;
    const int b = blockIdx.y;
    const int q = tid & 127;
    const int chunk = tid >> 7;
    const int s0 = chunk * 256;
    const unsigned s0u = __builtin_amdgcn_readfirstlane((unsigned)s0);
    const char* cp = (const char*)(pk + (size_t)b * S_) + (size_t)s0u * 16u;

    const int n = blockIdx.x * 128 + q;
    const float* p = xyz1 + ((size_t)b * N_ + n) * 3;
    const float px = p[0], py = p[1], pz = p[2];
    const float r1 = (px * px + py * py) + pz * pz;

    float e1 = 3.4e38f, e2 = 3.4e38f, e3 = 3.4e38f;
    int i1 = 0x7FFFFFFF, i2 = 0x7FFFFFFF, i3 = 0x7FFFFFFF;
    for (int g = 0; g < 16; ++g) {
        f32x16 c0, c1, c2, c3;
        asm volatile("s_load_dwordx16 %0, %4, 0\n\t"
                     "s_load_dwordx16 %1, %4, 64\n\t"
                     "s_load_dwordx16 %2, %4, 128\n\t"
                     "s_load_dwordx16 %3, %4, 192\n\t"
                     "s_waitcnt lgkmcnt(0)"
                     : "=&s"(c0), "=&s"(c1), "=&s"(c2), "=&s"(c3)
                     : "s"(cp + (size_t)g * 256));
#pragma unroll
        for (int j = 0; j < 16; ++j) {
            float sx = (j < 4) ? c0[4*j+0] : (j < 8) ? c1[4*(j-4)+0] : (j < 12) ? c2[4*(j-8)+0] : c3[4*(j-12)+0];
            float sy = (j < 4) ? c0[4*j+1] : (j < 8) ? c1[4*(j-4)+1] : (j < 12) ? c2[4*(j-8)+1] : c3[4*(j-12)+1];
            float sz = (j < 4) ? c0[4*j+2] : (j < 8) ? c1[4*(j-4)+2] : (j < 12) ? c2[4*(j-8)+2] : c3[4*(j-12)+2];
            float sr = (j < 4) ? c0[4*j+3] : (j < 8) ? c1[4*(j-4)+3] : (j < 12) ? c2[4*(j-8)+3] : c3[4*(j-12)+3];
            float dot = (px * sx + py * sy) + pz * sz;
            float d = (r1 - 2.0f * dot) + sr;
            const int s = s0 + g * 16 + j;
            bool lt1 = d < e1, lt2 = d < e2, lt3 = d < e3;
            float n1 = fminf(e1, d);
            float n2 = __builtin_amdgcn_fmed3f(d, e1, e2);
            float n3 = __builtin_amdgcn_fmed3f(d, e2, e3);
            int ni1 = lt1 ? s : i1;
            int ni2 = lt1 ? i1 : (lt2 ? s : i2);
            int ni3 = lt2 ? i2 : (lt3 ? s : i3);
            e1 = n1; e2 = n2; e3 = n3;
            i1 = ni1; i2 = ni2; i3 = ni3;
        }
    }
    pv[chunk][q][0] = f2u(e1); pv[chunk][q][1] = f2u(e2); pv[chunk][q][2] = f2u(e3);
    pi[chunk][q][0] = i1; pi[chunk][q][1] = i2; pi[chunk][q][2] = i3;
    __syncthreads();

    if (tid < 128) {
        float m1 = u2f(pv[0][tid][0]), m2 = u2f(pv[0][tid][1]), m3 = u2f(pv[0][tid][2]);
        int j1 = pi[0][tid][0], j2 = pi[0][tid][1], j3 = pi[0][tid][2];
#pragma unroll
        for (int c = 1; c < 8; ++c) {
#pragma unroll
            for (int e = 0; e < 3; ++e) {
                float x = u2f(pv[c][tid][e]);
                int   xi = pi[c][tid][e];
                bool lt1 = x < m1, lt2 = x < m2, lt3 = x < m3;
                float n1 = fminf(m1, x);
                float n2 = __builtin_amdgcn_fmed3f(x, m1, m2);
                float n3 = __builtin_amdgcn_fmed3f(x, m2, m3);
                int nj1 = lt1 ? xi : j1;
                int nj2 = lt1 ? j1 : (lt2 ? xi : j2);
                int nj3 = lt2 ? j2 : (lt3 ? xi : j3);
                m1 = n1; m2 = n2; m3 = n3;
                j1 = nj1; j2 = nj2; j3 = nj3;
            }
        }
        float ra = 1.0f / (m1 + 1e-8f);
        float rb = 1.0f / (m2 + 1e-8f);
        float rc = 1.0f / (m3 + 1e-8f);
        float sum = (ra + rb) + rc;
        size_t o = ((size_t)b * N_ + blockIdx.x * 128 + tid) * 3;
        nidx[o + 0] = j1; nidx[o + 1] = j2; nidx[o + 2] = j3;
        nw[o + 0] = ra / sum; nw[o + 1] = rb / sum; nw[o + 2] = rc / sum;
    }
}

// weights -> bf16
__global__ void cvtw_kernel(const float* __restrict__ w1, const float* __restrict__ w2,
                            unsigned short* __restrict__ w1b, unsigned short* __restrict__ w2b)
{
    int i = blockIdx.x * 256 + threadIdx.x;
    if (i < C1_ * CIN_) w1b[i] = f2bf(w1[i]);
    else {
        int j = i - C1_ * CIN_;
        if (j < C2_ * C1_) w2b[j] = f2bf(w2[j]);
    }
}

// ---------------------------------------------------------------------------
// GEMM1 FAT-STEP (byte-identical to passing rounds 14/18, best measured):
// BM=256 x BN=256 x BK=64, 8 waves (512 thr), 6 K-steps, 64 MFMA/wave/step.
// A built in-flight (concat p1 | interp p2). Fused bias + BN-stats. bf16 out.
// ---------------------------------------------------------------------------
__global__ __launch_bounds__(512) void gemm1_kernel(
    const unsigned short* __restrict__ W,    // w1b [256][384]
    const float* __restrict__ bias,
    const float* __restrict__ p1,
    const float* __restrict__ p2,
    const int* __restrict__ nidx,
    const float* __restrict__ nw,
    unsigned short* __restrict__ out,        // y1b [65536][256]
    float* __restrict__ sums, float* __restrict__ ssqs)
{
    __shared__ unsigned short As[8][256][8];   // 32 KiB
    __shared__ unsigned short Bs[8][256][8];   // 32 KiB
    __shared__ float csum[256], csq[256];
    __shared__ int   lidx[256][3];
    __shared__ float lw[256][3];
    const int tid = threadIdx.x;               // 0..511
    const int wave = tid >> 6, lane = tid & 63;
    const int chunkw = (blockIdx.x & 7) * (gridDim.x >> 3) + (blockIdx.x >> 3);
    const int r0 = chunkw * 256;
    const int wr = wave >> 2, wc = wave & 3;
    const int kh = lane >> 4, l16 = lane & 15;
    const int irow = tid & 255;                // row this thread stages
    const int hi = tid >> 8;                   // 0/1

    if (tid < 256) {
        csum[tid] = 0.f; csq[tid] = 0.f;
        const int row = r0 + tid;
        lidx[tid][0] = nidx[row * 3 + 0];
        lidx[tid][1] = nidx[row * 3 + 1];
        lidx[tid][2] = nidx[row * 3 + 2];
        lw[tid][0] = nw[row * 3 + 0];
        lw[tid][1] = nw[row * 3 + 1];
        lw[tid][2] = nw[row * 3 + 2];
    }
    __syncthreads();
    const int gj0 = lidx[irow][0], gj1 = lidx[irow][1], gj2 = lidx[irow][2];
    const float gw0 = lw[irow][0], gw1 = lw[irow][1], gw2 = lw[irow][2];
    const float* p2b = p2 + (size_t)(r0 >> 13) * S_ * D2_;   // block-uniform batch

    f32x4 acc[8][4];
#pragma unroll
    for (int m = 0; m < 8; ++m)
#pragma unroll
        for (int n = 0; n < 4; ++n)
            acc[m][n] = (f32x4){0.f, 0.f, 0.f, 0.f};

    for (int k0 = 0; k0 < CIN_; k0 += 64) {
        __syncthreads();   // previous step's LDS reads complete
        // stage B: 2048 slots, global_load_lds 16B each (4/thread)
#pragma unroll
        for (int t = 0; t < 4; ++t) {
            const int sb = t * 512 + wave * 64;          // wave-uniform
            const int s = sb + lane;
            const int bkg = s >> 8, bi = s & 255;
            const unsigned short* gB = W + (size_t)bi * CIN_ + k0 + bkg * 8;
            __builtin_amdgcn_global_load_lds(
                (const __attribute__((address_space(1))) void*)gB,
                (__attribute__((address_space(3))) void*)(&Bs[0][0][0] + (size_t)sb * 8),
                16, 0, 0);
        }
        // stage A: per thread 4 octets of its row (kg = 2t+hi)
#pragma unroll
        for (int t = 0; t < 4; ++t) {
            const int kg = t * 2 + hi;
            const int cc0 = k0 + kg * 8;
            short8v r;
            if (k0 < D1_) {          // whole step reads points1 (cc0 < 128)
                const float* qq = p1 + (size_t)(r0 + irow) * D1_ + cc0;
                float4 a = *(const float4*)qq;
                float4 bq = *(const float4*)(qq + 4);
                float tt[8] = {a.x, a.y, a.z, a.w, bq.x, bq.y, bq.z, bq.w};
#pragma unroll
                for (int j = 0; j < 8; ++j) r[j] = (short)f2bf(tt[j]);
            } else {                 // interp region
                const int cc = cc0 - D1_;
                const float* q0 = p2b + (size_t)gj0 * D2_ + cc;
                const float* q1 = p2b + (size_t)gj1 * D2_ + cc;
                const float* q2 = p2b + (size_t)gj2 * D2_ + cc;
                float4 x0 = *(const float4*)q0, x0b = *(const float4*)(q0 + 4);
                float4 x1 = *(const float4*)q1, x1b = *(const float4*)(q1 + 4);
                float4 x2 = *(const float4*)q2, x2b = *(const float4*)(q2 + 4);
                float a0[8] = {x0.x, x0.y, x0.z, x0.w, x0b.x, x0b.y, x0b.z, x0b.w};
                float a1[8] = {x1.x, x1.y, x1.z, x1.w, x1b.x, x1b.y, x1b.z, x1b.w};
                float a2[8] = {x2.x, x2.y, x2.z, x2.w, x2b.x, x2b.y, x2b.z, x2b.w};
#pragma unroll
                for (int j = 0; j < 8; ++j)
                    r[j] = (short)f2bf(a0[j] * gw0 + a1[j] * gw1 + a2[j] * gw2);
            }
            *(short8v*)&As[kg][irow][0] = r;
        }
        __syncthreads();

        // MFMA: 2 K=32 chunks, 8x4 frags -> 64 MFMA/wave/step
#pragma unroll
        for (int kk = 0; kk < 2; ++kk) {
            short8v af[8], bf[4];
#pragma unroll
            for (int m = 0; m < 8; ++m)
                af[m] = *(const short8v*)&As[kk * 4 + kh][wr * 128 + m * 16 + l16][0];
#pragma unroll
            for (int n = 0; n < 4; ++n)
                bf[n] = *(const short8v*)&Bs[kk * 4 + kh][wc * 64 + n * 16 + l16][0];
#pragma unroll
            for (int m = 0; m < 8; ++m)
#pragma unroll
                for (int n = 0; n < 4; ++n)
                    acc[m][n] = __builtin_amdgcn_mfma_f32_16x16x32_bf16(
                        af[m], bf[n], acc[m][n], 0, 0, 0);
        }
    }

    // epilogue: +bias, store, per-channel stats
#pragma unroll
    for (int n = 0; n < 4; ++n) {
        const int col = wc * 64 + n * 16 + l16;   // 0..255
        const float bv = bias[col];
        float s = 0.f, qs = 0.f;
#pragma unroll
        for (int m = 0; m < 8; ++m) {
            const int rl = wr * 128 + m * 16 + kh * 4;
#pragma unroll
            for (int j = 0; j < 4; ++j) {
                const float v = acc[m][n][j] + bv;
                s += v; qs += v * v;
                out[(size_t)(r0 + rl + j) * C1_ + col] = f2bf(v);
            }
        }
        atomicAdd(&csum[col], s);
        atomicAdd(&csq[col], qs);
    }
    __syncthreads();
    if (tid < 256) {
        atomicAdd(&sums[tid], csum[tid]);
        atomicAdd(&ssqs[tid], csq[tid]);
    }
}

// ---------------------------------------------------------------------------
// GEMM2 (byte-identical to passing rounds 10-18): A = relu(y1b*scale+shift)
// reg-staged; fused bias + stats. Output f32.
// ---------------------------------------------------------------------------
__global__ __launch_bounds__(256) void gemm2_kernel(
    const unsigned short* __restrict__ Abf,
    const unsigned short* __restrict__ W,
    const float* __restrict__ bias,
    const float* __restrict__ scale, const float* __restrict__ shift,
    float* __restrict__ outf,
    float* __restrict__ sums, float* __restrict__ ssqs)
{
    __shared__ unsigned short As[4][128][8];
    __shared__ unsigned short Bs[4][128][8];
    __shared__ float csum[128], csq[128];
    const int tid = threadIdx.x;
    const int wave = tid >> 6, lane = tid & 63;
    const int chunkw = (blockIdx.x & 7) * (gridDim.x >> 3) + (blockIdx.x >> 3);
    const int r0 = chunkw * 128;
    const int n0 = 0;
    const int wr = wave >> 1, wc = wave & 1;
    const int kh = lane >> 4, l16 = lane & 15;

    if (tid < 128) { csum[tid] = 0.f; csq[tid] = 0.f; }

    f32x4 acc[4][4];
#pragma unroll
    for (int m = 0; m < 4; ++m)
#pragma unroll
        for (int n = 0; n < 4; ++n)
            acc[m][n] = (f32x4){0.f, 0.f, 0.f, 0.f};

    const int slotbase = wave * 64;
    int rowA[2];
#pragma unroll
    for (int pp = 0; pp < 2; ++pp)
        rowA[pp] = r0 + ((pp * 256 + slotbase + lane) & 127);

    for (int k0 = 0; k0 < C1_; k0 += 32) {
        __syncthreads();
#pragma unroll
        for (int pp = 0; pp < 2; ++pp) {
            const int sb = pp * 256 + slotbase;
            const int s = sb + lane;
            const int kg = s >> 7, i = s & 127;
            const unsigned short* gB = W + (size_t)(n0 + i) * C1_ + k0 + kg * 8;
            __builtin_amdgcn_global_load_lds(
                (const __attribute__((address_space(1))) void*)gB,
                (__attribute__((address_space(3))) void*)(&Bs[0][0][0] + (size_t)sb * 8),
                16, 0, 0);
            const int c0 = k0 + kg * 8;
            short8v v = *(const short8v*)(Abf + (size_t)rowA[pp] * C1_ + c0);
            float4 sca = *(const float4*)(scale + c0);
            float4 scb = *(const float4*)(scale + c0 + 4);
            float4 sha = *(const float4*)(shift + c0);
            float4 shb = *(const float4*)(shift + c0 + 4);
            float sc[8] = {sca.x, sca.y, sca.z, sca.w, scb.x, scb.y, scb.z, scb.w};
            float sh[8] = {sha.x, sha.y, sha.z, sha.w, shb.x, shb.y, shb.z, shb.w};
            short8v r;
#pragma unroll
            for (int j = 0; j < 8; ++j) {
                float f = bf2f((unsigned short)v[j]);
                f = fmaxf(fmaf(f, sc[j], sh[j]), 0.0f);
                r[j] = (short)f2bf(f);
            }
            *(short8v*)&As[kg][s & 127][0] = r;
        }
        __syncthreads();

        short8v af[4], bf[4];
#pragma unroll
        for (int m = 0; m < 4; ++m)
            af[m] = *(const short8v*)&As[kh][wr * 64 + m * 16 + l16][0];
#pragma unroll
        for (int n = 0; n < 4; ++n)
            bf[n] = *(const short8v*)&Bs[kh][wc * 64 + n * 16 + l16][0];
#pragma unroll
        for (int m = 0; m < 4; ++m)
#pragma unroll
            for (int n = 0; n < 4; ++n)
                acc[m][n] = __builtin_amdgcn_mfma_f32_16x16x32_bf16(
                    af[m], bf[n], acc[m][n], 0, 0, 0);
    }

#pragma unroll
    for (int n = 0; n < 4; ++n) {
        const int cl = wc * 64 + n * 16 + l16;
        const int col = n0 + cl;
        const float bv = bias[col];
        float s = 0.f, qs = 0.f;
#pragma unroll
        for (int m = 0; m < 4; ++m) {
            const int rowb = r0 + wr * 64 + m * 16 + kh * 4;
#pragma unroll
            for (int j = 0; j < 4; ++j) {
                const float v = acc[m][n][j] + bv;
                s += v; qs += v * v;
                outf[(size_t)(rowb + j) * C2_ + col] = v;
            }
        }
        atomicAdd(&csum[cl], s);
        atomicAdd(&csq[cl], qs);
    }
    __syncthreads();
    if (tid < 128) {
        atomicAdd(&sums[n0 + tid], csum[tid]);
        atomicAdd(&ssqs[n0 + tid], csq[tid]);
    }
}

__global__ void finalize_kernel(const float* __restrict__ sums,
                                const float* __restrict__ ssqs,
                                const float* __restrict__ g,
                                const float* __restrict__ be,
                                float* __restrict__ scale,
                                float* __restrict__ shift, int C, float invCnt)
{
    int c = threadIdx.x;
    if (c < C) {
        float mu = sums[c] * invCnt;
        float var = ssqs[c] * invCnt - mu * mu;
        float sc = g[c] / sqrtf(var + 1e-5f);
        scale[c] = sc;
        shift[c] = be[c] - mu * sc;
    }
}

__global__ __launch_bounds__(256) void bnrelu_store_kernel(
    const float* __restrict__ y, const float* __restrict__ scale,
    const float* __restrict__ shift, float* __restrict__ out)
{
    int i = blockIdx.x * 256 + threadIdx.x;
    float4 v = ((const float4*)y)[i];
    int o = (i * 4) & (C2_ - 1);
    float4 sc = *(const float4*)(scale + o);
    float4 sh = *(const float4*)(shift + o);
    float4 r;
    r.x = fmaxf(fmaf(v.x, sc.x, sh.x), 0.0f);
    r.y = fmaxf(fmaf(v.y, sc.y, sh.y), 0.0f);
    r.z = fmaxf(fmaf(v.z, sc.z, sh.z), 0.0f);
    r.w = fmaxf(fmaf(v.w, sc.w, sh.w), 0.0f);
    ((float4*)out)[i] = r;
}

extern "C" void kernel_launch(void* const* d_in, const int* in_sizes, int n_in,
                              void* d_out, int out_size, void* d_ws, size_t ws_size,
                              hipStream_t stream)
{
    const float* xyz1    = (const float*)d_in[0];
    const float* xyz2    = (const float*)d_in[1];
    const float* points1 = (const float*)d_in[2];
    const float* points2 = (const float*)d_in[3];
    const float* w1  = (const float*)d_in[4];
    const float* b1  = (const float*)d_in[5];
    const float* g1  = (const float*)d_in[6];
    const float* be1 = (const float*)d_in[7];
    const float* w2  = (const float*)d_in[8];
    const float* b2  = (const float*)d_in[9];
    const float* g2  = (const float*)d_in[10];
    const float* be2 = (const float*)d_in[11];
    float* out = (float*)d_out;

    char* w = (char*)d_ws;
    float*          y2  = (float*)w;                             // 33,554,432
    unsigned short* y1b = (unsigned short*)(w + 50331648);       // 33,554,432
    char* tail = w + 83886080;
    int*   nidx = (int*)tail;                                    // 786,432
    float* nw   = (float*)(tail + 786432);                       // 786,432
    unsigned short* w1b = (unsigned short*)(tail + 1572864);     // 196,608
    unsigned short* w2b = (unsigned short*)(tail + 1769472);     // 65,536
    float* sum1   = (float*)(tail + 1835008);
    float* ssq1   = sum1 + 256;
    float* sum2   = ssq1 + 256;
    float* ssq2   = sum2 + 128;
    float* scale1 = ssq2 + 128;
    float* shift1 = scale1 + 256;
    float* scale2 = shift1 + 256;
    float* shift2 = scale2 + 128;
    float4* pk    = (float4*)(tail + 1843200);                   // 262,144

    hipMemsetAsync(sum1, 0, (256 + 256 + 128 + 128) * sizeof(float), stream);

    cvtw_kernel<<<dim3((C1_ * CIN_ + C2_ * C1_ + 255) / 256), 256, 0, stream>>>(w1, w2, w1b, w2b);
    pack_kernel<<<dim3(B_ * S_ / 256), 256, 0, stream>>>(xyz2, pk);

    nn3_kernel<<<dim3(N_ / 128, B_), 1024, 0, stream>>>(xyz1, pk, nidx, nw);

    gemm1_kernel<<<dim3(ROWS_ / 256), 512, 0, stream>>>(
        w1b, b1, points1, points2, nidx, nw, y1b, sum1, ssq1);
    finalize_kernel<<<1, 256, 0, stream>>>(sum1, ssq1, g1, be1, scale1, shift1, C1_, 1.0f / ROWS_);

    gemm2_kernel<<<dim3(ROWS_ / 128), 256, 0, stream>>>(
        y1b, w2b, b2, scale1, shift1, y2, sum2, ssq2);
    finalize_kernel<<<1, 256, 0, stream>>>(sum2, ssq2, g2, be2, scale2, shift2, C2_, 1.0f / ROWS_);

    bnrelu_store_kernel<<<dim3(ROWS_ * C2_ / 4 / 256), 256, 0, stream>>>(y2, scale2, shift2, out);
}